// Round 7
// baseline (123.327 us; speedup 1.0000x reference)
//
#include <hip/hip_runtime.h>
#include <math.h>

typedef float f32x4 __attribute__((ext_vector_type(4)));
typedef __bf16 bf16x8 __attribute__((ext_vector_type(8)));
typedef unsigned short u16x8 __attribute__((ext_vector_type(8)));

__device__ __forceinline__ unsigned short f2bf(float f) {
    union { float f; unsigned int u; } v; v.f = f;
    unsigned int u = v.u;
    return (unsigned short)((u + 0x7fffu + ((u >> 16) & 1u)) >> 16);  // RNE
}
__device__ __forceinline__ float bf_lo(unsigned int d) {
    union { unsigned int u; float f; } v; v.u = d << 16; return v.f;
}
__device__ __forceinline__ float bf_hi(unsigned int d) {
    union { unsigned int u; float f; } v; v.u = d & 0xffff0000u; return v.f;
}
__device__ __forceinline__ float sigmoidf_(float v) {
    return 1.f / (1.f + __expf(-v));
}

// ---------------------------------------------------------------------------
// Kernel 1: fused convert + MFMA bf16 GEMM.  C[m][n] = sum_w A[m][w]*B[n][w].
//  left  (t<32):  A = x^T tile (transpose+cvt in LDS), B = W[e][0:256]
//                 -> Lp[b][k][e] = C + b_lin[e]   (fp32)
//  right (t>=32): A = W[e][256:512], B = x^T tile
//                 -> R2[b][(e>>3)*2048 + j*8 + (e&7)] = bf16(C)
// ---------------------------------------------------------------------------
__global__ __launch_bounds__(256) void mfma_gemm_kernel(
    const float* __restrict__ x,      // (8,256,256) x[b][w][k]
    const float* __restrict__ W,      // (512,512)
    const float* __restrict__ b_lin,  // (512)
    float* __restrict__ Lp,           // (8,256,512)
    unsigned short* __restrict__ R2)  // (8, 512e x 256j packed)
{
    const int b = blockIdx.y;
    const int t = blockIdx.x;
    const bool left = (t < 32);
    int m0, n0;
    if (left) { m0 = (t >> 3) * 64; n0 = (t & 7) * 64; }
    else      { const int tt = t - 32; m0 = (tt >> 2) * 64; n0 = (tt & 3) * 64; }

    __shared__ unsigned short As[64][72];
    __shared__ unsigned short Bs[64][72];

    unsigned short (*Ts)[72] = left ? As : Bs;   // x^T tile
    unsigned short (*Ds)[72] = left ? Bs : As;   // W tile
    const int cbase = left ? m0 : n0;            // x column base (k or j)
    const int rbase = left ? n0 : m0;            // W row base (e)
    const int coff  = left ? 0 : 256;            // W column offset

    const int tid  = threadIdx.x;
    const int wv   = tid >> 6;
    const int lane = tid & 63;
    const int wy = wv >> 1, wx = wv & 1;
    const int lr = lane & 15;
    const int lk = lane >> 4;

    const float* xb = x + b * 65536;

    f32x4 acc[2][2];
    #pragma unroll
    for (int i = 0; i < 2; i++)
        #pragma unroll
        for (int jj = 0; jj < 2; jj++) acc[i][jj] = (f32x4){0.f, 0.f, 0.f, 0.f};

    const int wl = tid >> 4;         // 0..15
    const int kg = tid & 15;         // 0..15
    const int dr = tid >> 2;         // 0..63
    const int dc = (tid & 3) * 16;

    for (int k0 = 0; k0 < 256; k0 += 64) {
        #pragma unroll
        for (int p = 0; p < 4; p++) {
            const int w = wl + 16 * p;
            const float4 v = *(const float4*)(xb + (k0 + w) * 256 + cbase + kg * 4);
            Ts[kg * 4 + 0][w] = f2bf(v.x);
            Ts[kg * 4 + 1][w] = f2bf(v.y);
            Ts[kg * 4 + 2][w] = f2bf(v.z);
            Ts[kg * 4 + 3][w] = f2bf(v.w);
        }
        {
            const float* src = W + (rbase + dr) * 512 + coff + k0 + dc;
            const float4 v0 = *(const float4*)(src);
            const float4 v1 = *(const float4*)(src + 4);
            const float4 v2 = *(const float4*)(src + 8);
            const float4 v3 = *(const float4*)(src + 12);
            u16x8 o0, o1;
            o0[0] = f2bf(v0.x); o0[1] = f2bf(v0.y); o0[2] = f2bf(v0.z); o0[3] = f2bf(v0.w);
            o0[4] = f2bf(v1.x); o0[5] = f2bf(v1.y); o0[6] = f2bf(v1.z); o0[7] = f2bf(v1.w);
            o1[0] = f2bf(v2.x); o1[1] = f2bf(v2.y); o1[2] = f2bf(v2.z); o1[3] = f2bf(v2.w);
            o1[4] = f2bf(v3.x); o1[5] = f2bf(v3.y); o1[6] = f2bf(v3.z); o1[7] = f2bf(v3.w);
            *(u16x8*)&Ds[dr][dc]     = o0;
            *(u16x8*)&Ds[dr][dc + 8] = o1;
        }
        __syncthreads();
        #pragma unroll
        for (int kk = 0; kk < 64; kk += 32) {
            const bf16x8 a0 = *(const bf16x8*)&As[wy * 32 + lr][kk + lk * 8];
            const bf16x8 a1 = *(const bf16x8*)&As[wy * 32 + 16 + lr][kk + lk * 8];
            const bf16x8 b0 = *(const bf16x8*)&Bs[wx * 32 + lr][kk + lk * 8];
            const bf16x8 b1 = *(const bf16x8*)&Bs[wx * 32 + 16 + lr][kk + lk * 8];
            acc[0][0] = __builtin_amdgcn_mfma_f32_16x16x32_bf16(a0, b0, acc[0][0], 0, 0, 0);
            acc[0][1] = __builtin_amdgcn_mfma_f32_16x16x32_bf16(a0, b1, acc[0][1], 0, 0, 0);
            acc[1][0] = __builtin_amdgcn_mfma_f32_16x16x32_bf16(a1, b0, acc[1][0], 0, 0, 0);
            acc[1][1] = __builtin_amdgcn_mfma_f32_16x16x32_bf16(a1, b1, acc[1][1], 0, 0, 0);
        }
        __syncthreads();
    }

    // C/D layout: col = lane&15, row = (lane>>4)*4 + reg
    if (left) {
        #pragma unroll
        for (int mi = 0; mi < 2; mi++) {
            #pragma unroll
            for (int ni = 0; ni < 2; ni++) {
                const int row = m0 + wy * 32 + mi * 16 + lk * 4;   // k
                const int col = n0 + wx * 32 + ni * 16 + lr;       // e
                const float bl = b_lin[col];
                #pragma unroll
                for (int r = 0; r < 4; r++)
                    Lp[b * 131072 + (row + r) * 512 + col] = acc[mi][ni][r] + bl;
            }
        }
    } else {
        unsigned short* R2b = R2 + b * 131072;
        #pragma unroll
        for (int mi = 0; mi < 2; mi++) {
            #pragma unroll
            for (int ni = 0; ni < 2; ni++) {
                const int row = m0 + wy * 32 + mi * 16 + lk * 4;   // e base (4)
                const int col = n0 + wx * 32 + ni * 16 + lr;       // j
                ushort4 o;
                o.x = f2bf(acc[mi][ni][0]);
                o.y = f2bf(acc[mi][ni][1]);
                o.z = f2bf(acc[mi][ni][2]);
                o.w = f2bf(acc[mi][ni][3]);
                *(ushort4*)(R2b + (row >> 3) * 2048 + col * 8 + (row & 7)) = o;
            }
        }
    }
}

// ---------------------------------------------------------------------------
// Kernel 2: score + softmax + MFMA matvec + sigmoid + T-store.
// grid 512 = (i-tile of 4) x (b = blk&7); 1024 thr = 256 j x 4 e-quarters.
// i-tile 4 keeps the wave-uniform L working set (4*2KB + a 0.5KB) inside the
// 16KB scalar L1 -> s_loads hit (i-tile 8 thrashed it, round 6).
// score[i][j] = 0.6*(uL[i]+uR[j]) + 0.4*sum_e a[e]*|L[i,e]+R[e,j]| + bias
// ---------------------------------------------------------------------------
__global__ __launch_bounds__(1024, 4) void attn_kernel(
    const float* __restrict__ x,              // (8,256,256)
    const float* __restrict__ Lp,             // (8,256,512) fp32, b_lin folded
    const unsigned int* __restrict__ R2u,     // packed bf16 pairs
    const float* __restrict__ a,              // (512)
    const float* __restrict__ bias,           // (256,256)
    float* __restrict__ out)                  // (8,256,256)
{
    const int b   = blockIdx.x & 7;
    const int i0  = (blockIdx.x >> 3) * 4;
    const int tid = threadIdx.x;
    const int j   = tid & 255;
    const int q   = __builtin_amdgcn_readfirstlane(tid >> 8);

    __shared__ float acc2P[4096];             // [4 q][4 i][256 j]
    __shared__ float rgp[1024];               // [4 q][256 j]
    __shared__ float atf[1024];               // [4 i][256 j]
    __shared__ float u15s[4];
    __shared__ unsigned short atbf[16 * 264]; // bf16 attn rows (0..3 valid)

    // ---- uL: waves 0..3, u15s[i] = 0.6 * sum_e a[e]*L[i,e]
    if (tid < 256) {
        const int i = tid >> 6, lane = tid & 63;
        const float* Lr = Lp + b * 131072 + (i0 + i) * 512 + lane * 8;
        const float* ar = a + lane * 8;
        const float4 la = *(const float4*)Lr;
        const float4 lb = *(const float4*)(Lr + 4);
        const float4 ca = *(const float4*)ar;
        const float4 cb = *(const float4*)(ar + 4);
        float p = la.x * ca.x + la.y * ca.y + la.z * ca.z + la.w * ca.w
                + lb.x * cb.x + lb.y * cb.y + lb.z * cb.z + lb.w * cb.w;
        #pragma unroll
        for (int off = 32; off; off >>= 1) p += __shfl_xor(p, off);
        if (lane == 0) u15s[i] = 0.6f * p;
    }

    // ---- score: 128 e per thread, 4 i rows; L/a wave-uniform -> s_loads
    const float* Lq = Lp + b * 131072 + i0 * 512 + q * 128;
    const float* aq = a + q * 128;
    const uint4* Rq = (const uint4*)(R2u + b * 65536) + (q * 16) * 256 + j;

    float acc0 = 0.f, acc1 = 0.f, acc2 = 0.f, acc3 = 0.f, rsum = 0.f;

    uint4 cur = Rq[0];
    #pragma unroll 2
    for (int tk = 0; tk < 16; tk++) {
        uint4 nxt;
        if (tk < 15) nxt = Rq[(tk + 1) * 256];
        float r[8];
        r[0] = bf_lo(cur.x); r[1] = bf_hi(cur.x);
        r[2] = bf_lo(cur.y); r[3] = bf_hi(cur.y);
        r[4] = bf_lo(cur.z); r[5] = bf_hi(cur.z);
        r[6] = bf_lo(cur.w); r[7] = bf_hi(cur.w);
        #pragma unroll
        for (int s = 0; s < 8; s++) {
            const int el = tk * 8 + s;
            const float ae = aq[el];
            rsum = fmaf(ae, r[s], rsum);
            const float p0 = Lq[el]        + r[s];
            const float p1 = Lq[512 + el]  + r[s];
            const float p2 = Lq[1024 + el] + r[s];
            const float p3 = Lq[1536 + el] + r[s];
            acc0 = fmaf(ae, fabsf(p0), acc0);
            acc1 = fmaf(ae, fabsf(p1), acc1);
            acc2 = fmaf(ae, fabsf(p2), acc2);
            acc3 = fmaf(ae, fabsf(p3), acc3);
        }
        cur = nxt;
    }
    {
        float* dst = acc2P + q * 1024 + j;
        dst[0]   = acc0;
        dst[256] = acc1;
        dst[512] = acc2;
        dst[768] = acc3;
        rgp[q * 256 + j] = rsum;
    }
    // zero unused atbf rows 4..15 while waves 4..15 are otherwise idle pre-sync
    if (tid >= 512 && tid < 768) {
        for (int z = tid - 512; z < 12 * 264; z += 256) atbf[4 * 264 + z] = 0;
    }
    __syncthreads();

    // ---- combine
    if (tid < 256) {
        const float uR = rgp[j] + rgp[256 + j] + rgp[512 + j] + rgp[768 + j];
        #pragma unroll
        for (int i = 0; i < 4; i++) {
            const float ab = acc2P[i * 256 + j] + acc2P[1024 + i * 256 + j]
                           + acc2P[2048 + i * 256 + j] + acc2P[3072 + i * 256 + j];
            atf[i * 256 + j] = u15s[i] + 0.6f * uR + 0.4f * ab
                             + bias[(i0 + i) * 256 + j];
        }
    }
    __syncthreads();

    // ---- softmax: wave i (tid<256) -> row i; write bf16 attn
    if (tid < 256) {
        const int i = tid >> 6, lane = tid & 63;
        float v[4];
        float m = -1e30f;
        #pragma unroll
        for (int u = 0; u < 4; u++) {
            v[u] = atf[i * 256 + lane + 64 * u];
            m = fmaxf(m, v[u]);
        }
        #pragma unroll
        for (int off = 32; off; off >>= 1) m = fmaxf(m, __shfl_xor(m, off));
        float s = 0.f;
        #pragma unroll
        for (int u = 0; u < 4; u++) { v[u] = __expf(v[u] - m); s += v[u]; }
        #pragma unroll
        for (int off = 32; off; off >>= 1) s += __shfl_xor(s, off);
        const float inv = 1.f / s;
        #pragma unroll
        for (int u = 0; u < 4; u++)
            atbf[i * 264 + lane + 64 * u] = f2bf(v[u] * inv);
    }
    __syncthreads();

    // ---- matvec via MFMA: D[i][w] = sum_j attn[i][j] * x[b][w][j]
    {
        const int nt = tid >> 6;          // 0..15 w-tiles
        const int lane = tid & 63;
        const int lr = lane & 15;
        const int lk = lane >> 4;
        f32x4 hacc = (f32x4){0.f, 0.f, 0.f, 0.f};
        const float* xw = x + b * 65536 + (nt * 16 + lr) * 256;
        #pragma unroll
        for (int kt = 0; kt < 8; kt++) {
            const bf16x8 av = *(const bf16x8*)&atbf[lr * 264 + kt * 32 + lk * 8];
            const float4 f0 = *(const float4*)(xw + kt * 32 + lk * 8);
            const float4 f1 = *(const float4*)(xw + kt * 32 + lk * 8 + 4);
            u16x8 bu;
            bu[0] = f2bf(f0.x); bu[1] = f2bf(f0.y); bu[2] = f2bf(f0.z); bu[3] = f2bf(f0.w);
            bu[4] = f2bf(f1.x); bu[5] = f2bf(f1.y); bu[6] = f2bf(f1.z); bu[7] = f2bf(f1.w);
            const bf16x8 bv = *(const bf16x8*)&bu;
            hacc = __builtin_amdgcn_mfma_f32_16x16x32_bf16(av, bv, hacc, 0, 0, 0);
        }
        // D: col(lane&15)=w, row(lk*4+r)=i; valid i rows 0..3 -> lk==0
        if (lk == 0) {
            float4 o;
            o.x = sigmoidf_(hacc[0]);
            o.y = sigmoidf_(hacc[1]);
            o.z = sigmoidf_(hacc[2]);
            o.w = sigmoidf_(hacc[3]);
            *(float4*)(out + b * 65536 + (nt * 16 + lr) * 256 + i0) = o;
        }
    }
}

extern "C" void kernel_launch(void* const* d_in, const int* in_sizes, int n_in,
                              void* d_out, int out_size, void* d_ws, size_t ws_size,
                              hipStream_t stream) {
    const float* x     = (const float*)d_in[0];
    const float* W     = (const float*)d_in[1];
    const float* b_lin = (const float*)d_in[2];
    const float* a     = (const float*)d_in[3];
    const float* bias  = (const float*)d_in[4];
    float* out = (float*)d_out;

    char* ws = (char*)d_ws;
    float*          Lp = (float*)ws;                          // 4 MB
    unsigned short* R2 = (unsigned short*)(ws + (4 << 20));   // 2 MB

    mfma_gemm_kernel<<<dim3(64, 8), 256, 0, stream>>>(x, W, b_lin, Lp, R2);
    attn_kernel<<<512, 1024, 0, stream>>>(x, Lp, (const unsigned int*)R2, a, bias, out);
}

// Round 8
// 107.764 us; speedup vs baseline: 1.1444x; 1.1444x over previous
//
#include <hip/hip_runtime.h>
#include <math.h>

typedef float f32x4 __attribute__((ext_vector_type(4)));
typedef __bf16 bf16x8 __attribute__((ext_vector_type(8)));
typedef unsigned short u16x8 __attribute__((ext_vector_type(8)));

__device__ __forceinline__ unsigned short f2bf(float f) {
    union { float f; unsigned int u; } v; v.f = f;
    unsigned int u = v.u;
    return (unsigned short)((u + 0x7fffu + ((u >> 16) & 1u)) >> 16);  // RNE
}
__device__ __forceinline__ float bf_lo(unsigned int d) {
    union { unsigned int u; float f; } v; v.u = d << 16; return v.f;
}
__device__ __forceinline__ float bf_hi(unsigned int d) {
    union { unsigned int u; float f; } v; v.u = d & 0xffff0000u; return v.f;
}
__device__ __forceinline__ float sigmoidf_(float v) {
    return 1.f / (1.f + __expf(-v));
}

// ---------------------------------------------------------------------------
// Kernel 1: fused convert + MFMA bf16 GEMM.  C[m][n] = sum_w A[m][w]*B[n][w].
//  left  (t<32):  A = x^T tile (transpose+cvt in LDS), B = W[e][0:256]
//                 -> Lp[b][k][e] = C + b_lin[e]   (fp32)
//  right (t>=32): A = W[e][256:512], B = x^T tile
//                 -> R2[b][(e>>3)*2048 + j*8 + (e&7)] = bf16(C)
// ---------------------------------------------------------------------------
__global__ __launch_bounds__(256) void mfma_gemm_kernel(
    const float* __restrict__ x,      // (8,256,256) x[b][w][k]
    const float* __restrict__ W,      // (512,512)
    const float* __restrict__ b_lin,  // (512)
    float* __restrict__ Lp,           // (8,256,512)
    unsigned short* __restrict__ R2)  // (8, 512e x 256j packed)
{
    const int b = blockIdx.y;
    const int t = blockIdx.x;
    const bool left = (t < 32);
    int m0, n0;
    if (left) { m0 = (t >> 3) * 64; n0 = (t & 7) * 64; }
    else      { const int tt = t - 32; m0 = (tt >> 2) * 64; n0 = (tt & 3) * 64; }

    __shared__ unsigned short As[64][72];
    __shared__ unsigned short Bs[64][72];

    unsigned short (*Ts)[72] = left ? As : Bs;   // x^T tile
    unsigned short (*Ds)[72] = left ? Bs : As;   // W tile
    const int cbase = left ? m0 : n0;            // x column base (k or j)
    const int rbase = left ? n0 : m0;            // W row base (e)
    const int coff  = left ? 0 : 256;            // W column offset

    const int tid  = threadIdx.x;
    const int wv   = tid >> 6;
    const int lane = tid & 63;
    const int wy = wv >> 1, wx = wv & 1;
    const int lr = lane & 15;
    const int lk = lane >> 4;

    const float* xb = x + b * 65536;

    f32x4 acc[2][2];
    #pragma unroll
    for (int i = 0; i < 2; i++)
        #pragma unroll
        for (int jj = 0; jj < 2; jj++) acc[i][jj] = (f32x4){0.f, 0.f, 0.f, 0.f};

    const int wl = tid >> 4;         // 0..15
    const int kg = tid & 15;         // 0..15
    const int dr = tid >> 2;         // 0..63
    const int dc = (tid & 3) * 16;

    for (int k0 = 0; k0 < 256; k0 += 64) {
        #pragma unroll
        for (int p = 0; p < 4; p++) {
            const int w = wl + 16 * p;
            const float4 v = *(const float4*)(xb + (k0 + w) * 256 + cbase + kg * 4);
            Ts[kg * 4 + 0][w] = f2bf(v.x);
            Ts[kg * 4 + 1][w] = f2bf(v.y);
            Ts[kg * 4 + 2][w] = f2bf(v.z);
            Ts[kg * 4 + 3][w] = f2bf(v.w);
        }
        {
            const float* src = W + (rbase + dr) * 512 + coff + k0 + dc;
            const float4 v0 = *(const float4*)(src);
            const float4 v1 = *(const float4*)(src + 4);
            const float4 v2 = *(const float4*)(src + 8);
            const float4 v3 = *(const float4*)(src + 12);
            u16x8 o0, o1;
            o0[0] = f2bf(v0.x); o0[1] = f2bf(v0.y); o0[2] = f2bf(v0.z); o0[3] = f2bf(v0.w);
            o0[4] = f2bf(v1.x); o0[5] = f2bf(v1.y); o0[6] = f2bf(v1.z); o0[7] = f2bf(v1.w);
            o1[0] = f2bf(v2.x); o1[1] = f2bf(v2.y); o1[2] = f2bf(v2.z); o1[3] = f2bf(v2.w);
            o1[4] = f2bf(v3.x); o1[5] = f2bf(v3.y); o1[6] = f2bf(v3.z); o1[7] = f2bf(v3.w);
            *(u16x8*)&Ds[dr][dc]     = o0;
            *(u16x8*)&Ds[dr][dc + 8] = o1;
        }
        __syncthreads();
        #pragma unroll
        for (int kk = 0; kk < 64; kk += 32) {
            const bf16x8 a0 = *(const bf16x8*)&As[wy * 32 + lr][kk + lk * 8];
            const bf16x8 a1 = *(const bf16x8*)&As[wy * 32 + 16 + lr][kk + lk * 8];
            const bf16x8 b0 = *(const bf16x8*)&Bs[wx * 32 + lr][kk + lk * 8];
            const bf16x8 b1 = *(const bf16x8*)&Bs[wx * 32 + 16 + lr][kk + lk * 8];
            acc[0][0] = __builtin_amdgcn_mfma_f32_16x16x32_bf16(a0, b0, acc[0][0], 0, 0, 0);
            acc[0][1] = __builtin_amdgcn_mfma_f32_16x16x32_bf16(a0, b1, acc[0][1], 0, 0, 0);
            acc[1][0] = __builtin_amdgcn_mfma_f32_16x16x32_bf16(a1, b0, acc[1][0], 0, 0, 0);
            acc[1][1] = __builtin_amdgcn_mfma_f32_16x16x32_bf16(a1, b1, acc[1][1], 0, 0, 0);
        }
        __syncthreads();
    }

    // C/D layout: col = lane&15, row = (lane>>4)*4 + reg
    if (left) {
        #pragma unroll
        for (int mi = 0; mi < 2; mi++) {
            #pragma unroll
            for (int ni = 0; ni < 2; ni++) {
                const int row = m0 + wy * 32 + mi * 16 + lk * 4;   // k
                const int col = n0 + wx * 32 + ni * 16 + lr;       // e
                const float bl = b_lin[col];
                #pragma unroll
                for (int r = 0; r < 4; r++)
                    Lp[b * 131072 + (row + r) * 512 + col] = acc[mi][ni][r] + bl;
            }
        }
    } else {
        unsigned short* R2b = R2 + b * 131072;
        #pragma unroll
        for (int mi = 0; mi < 2; mi++) {
            #pragma unroll
            for (int ni = 0; ni < 2; ni++) {
                const int row = m0 + wy * 32 + mi * 16 + lk * 4;   // e base (4)
                const int col = n0 + wx * 32 + ni * 16 + lr;       // j
                ushort4 o;
                o.x = f2bf(acc[mi][ni][0]);
                o.y = f2bf(acc[mi][ni][1]);
                o.z = f2bf(acc[mi][ni][2]);
                o.w = f2bf(acc[mi][ni][3]);
                *(ushort4*)(R2b + (row >> 3) * 2048 + col * 8 + (row & 7)) = o;
            }
        }
    }
}

// ---------------------------------------------------------------------------
// Kernel 2: score + softmax + MFMA matvec + sigmoid + T-store.
// grid 512 = (i-tile of 4) x (b = blk&7, XCD-local); 512 thr = 256 j x 2 e-h.
// L staged TRANSPOSED in LDS as Lt[e][4i] (16B rows): the inner loop reads all
// 4 i-values for an e with ONE ds_read_b128 same-address broadcast (free of
// conflicts), killing the per-row vector/scalar global loads of rounds 6/7.
// score[i][j] = 0.6*(uL[i]+uR[j]) + 0.4*sum_e a[e]*|L[i,e]+R[e,j]| + bias
// ---------------------------------------------------------------------------
__global__ __launch_bounds__(512, 8) void attn_kernel(
    const float* __restrict__ x,              // (8,256,256)
    const float* __restrict__ Lp,             // (8,256,512) fp32, b_lin folded
    const unsigned int* __restrict__ R2u,     // packed bf16 pairs
    const float* __restrict__ a,              // (512)
    const float* __restrict__ bias,           // (256,256)
    float* __restrict__ out)                  // (8,256,256)
{
    const int b   = blockIdx.x & 7;
    const int i0  = (blockIdx.x >> 3) * 4;
    const int tid = threadIdx.x;
    const int j   = tid & 255;
    const int eh  = tid >> 8;                 // e-half 0..1

    __shared__ float Lt[512][4];              // 8 KB   [e][i] transposed L
    __shared__ float aS[512];                 // 2 KB
    __shared__ float acc2P[2][4][256];        // 8 KB
    __shared__ float rgp[2][256];             // 2 KB
    __shared__ float u15s[4];
    __shared__ unsigned short atbf[16 * 264]; // 8.25 KB (rows 4..15 unused)

    // ---- stage Lt (transpose via LDS) + aS
    {
        const int i  = tid >> 7;              // 0..3
        const int e0 = (tid & 127) * 4;
        const float4 v = *(const float4*)(Lp + b * 131072 + (i0 + i) * 512 + e0);
        Lt[e0 + 0][i] = v.x;
        Lt[e0 + 1][i] = v.y;
        Lt[e0 + 2][i] = v.z;
        Lt[e0 + 3][i] = v.w;
        aS[tid] = a[tid];
    }

    // ---- uL: waves 0..3, u15s[i] = 0.6 * sum_e a[e]*L[i,e]  (global reads)
    if (tid < 256) {
        const int i = tid >> 6, lane = tid & 63;
        const float* Lr = Lp + b * 131072 + (i0 + i) * 512 + lane * 8;
        const float* ar = a + lane * 8;
        const float4 la = *(const float4*)Lr;
        const float4 lb = *(const float4*)(Lr + 4);
        const float4 ca = *(const float4*)ar;
        const float4 cb = *(const float4*)(ar + 4);
        float p = la.x * ca.x + la.y * ca.y + la.z * ca.z + la.w * ca.w
                + lb.x * cb.x + lb.y * cb.y + lb.z * cb.z + lb.w * cb.w;
        #pragma unroll
        for (int off = 32; off; off >>= 1) p += __shfl_xor(p, off);
        if (lane == 0) u15s[i] = 0.6f * p;
    }
    __syncthreads();

    // ---- score: 256 e per thread (e-half), 4 i rows via Lt b128 broadcasts
    const float* aq = aS + eh * 256;
    const float (*Ltq)[4] = (const float (*)[4])(Lt + eh * 256);
    const uint4* Rq = (const uint4*)(R2u + b * 65536) + (eh * 32) * 256 + j;

    float acc0 = 0.f, acc1 = 0.f, acc2 = 0.f, acc3 = 0.f, rsum = 0.f;

    uint4 cur = Rq[0];
    for (int tk = 0; tk < 32; tk++) {
        uint4 nxt;
        if (tk < 31) nxt = Rq[(tk + 1) * 256];
        float r[8];
        r[0] = bf_lo(cur.x); r[1] = bf_hi(cur.x);
        r[2] = bf_lo(cur.y); r[3] = bf_hi(cur.y);
        r[4] = bf_lo(cur.z); r[5] = bf_hi(cur.z);
        r[6] = bf_lo(cur.w); r[7] = bf_hi(cur.w);
        #pragma unroll
        for (int q2 = 0; q2 < 2; q2++) {
            const float4 av4 = *(const float4*)&aq[tk * 8 + q2 * 4];
            #pragma unroll
            for (int s = 0; s < 4; s++) {
                const int e = tk * 8 + q2 * 4 + s;
                const float4 lv = *(const float4*)Ltq[e];   // ds_read_b128 bcast
                const float ae = ((const float*)&av4)[s];
                const float rv = r[q2 * 4 + s];
                rsum = fmaf(ae, rv, rsum);
                acc0 = fmaf(ae, fabsf(lv.x + rv), acc0);
                acc1 = fmaf(ae, fabsf(lv.y + rv), acc1);
                acc2 = fmaf(ae, fabsf(lv.z + rv), acc2);
                acc3 = fmaf(ae, fabsf(lv.w + rv), acc3);
            }
        }
        cur = nxt;
    }
    acc2P[eh][0][j] = acc0;
    acc2P[eh][1][j] = acc1;
    acc2P[eh][2][j] = acc2;
    acc2P[eh][3][j] = acc3;
    rgp[eh][j] = rsum;
    __syncthreads();

    // ---- softmax (combine folded in): wave i (tid<256) -> row i
    if (tid < 256) {
        const int i = tid >> 6, lane = tid & 63;
        const float u15 = u15s[i];
        float v[4];
        float m = -1e30f;
        #pragma unroll
        for (int u = 0; u < 4; u++) {
            const int jj = lane + 64 * u;
            const float uR = rgp[0][jj] + rgp[1][jj];
            const float ab = acc2P[0][i][jj] + acc2P[1][i][jj];
            v[u] = u15 + 0.6f * uR + 0.4f * ab + bias[(i0 + i) * 256 + jj];
            m = fmaxf(m, v[u]);
        }
        #pragma unroll
        for (int off = 32; off; off >>= 1) m = fmaxf(m, __shfl_xor(m, off));
        float s = 0.f;
        #pragma unroll
        for (int u = 0; u < 4; u++) { v[u] = __expf(v[u] - m); s += v[u]; }
        #pragma unroll
        for (int off = 32; off; off >>= 1) s += __shfl_xor(s, off);
        const float inv = 1.f / s;
        #pragma unroll
        for (int u = 0; u < 4; u++)
            atbf[i * 264 + lane + 64 * u] = f2bf(v[u] * inv);
    }
    __syncthreads();

    // ---- matvec via MFMA: D[i][w] = sum_j attn[i][j] * x[b][w][j]
    // 8 waves; wave wv handles w-tiles wv and wv+8. A rows 4..15 are garbage
    // LDS but only pollute D rows 4..15, which are never stored (lk==0 only).
    {
        const int wvv  = tid >> 6;
        const int lane = tid & 63;
        const int lr = lane & 15;
        const int lk = lane >> 4;
        #pragma unroll
        for (int half = 0; half < 2; half++) {
            const int nt = wvv + half * 8;
            f32x4 hacc = (f32x4){0.f, 0.f, 0.f, 0.f};
            const float* xw = x + b * 65536 + (nt * 16 + lr) * 256;
            #pragma unroll
            for (int kt = 0; kt < 8; kt++) {
                const bf16x8 av = *(const bf16x8*)&atbf[lr * 264 + kt * 32 + lk * 8];
                const float4 f0 = *(const float4*)(xw + kt * 32 + lk * 8);
                const float4 f1 = *(const float4*)(xw + kt * 32 + lk * 8 + 4);
                u16x8 bu;
                bu[0] = f2bf(f0.x); bu[1] = f2bf(f0.y); bu[2] = f2bf(f0.z); bu[3] = f2bf(f0.w);
                bu[4] = f2bf(f1.x); bu[5] = f2bf(f1.y); bu[6] = f2bf(f1.z); bu[7] = f2bf(f1.w);
                const bf16x8 bv = *(const bf16x8*)&bu;
                hacc = __builtin_amdgcn_mfma_f32_16x16x32_bf16(av, bv, hacc, 0, 0, 0);
            }
            if (lk == 0) {
                float4 o;
                o.x = sigmoidf_(hacc[0]);
                o.y = sigmoidf_(hacc[1]);
                o.z = sigmoidf_(hacc[2]);
                o.w = sigmoidf_(hacc[3]);
                *(float4*)(out + b * 65536 + (nt * 16 + lr) * 256 + i0) = o;
            }
        }
    }
}

extern "C" void kernel_launch(void* const* d_in, const int* in_sizes, int n_in,
                              void* d_out, int out_size, void* d_ws, size_t ws_size,
                              hipStream_t stream) {
    const float* x     = (const float*)d_in[0];
    const float* W     = (const float*)d_in[1];
    const float* b_lin = (const float*)d_in[2];
    const float* a     = (const float*)d_in[3];
    const float* bias  = (const float*)d_in[4];
    float* out = (float*)d_out;

    char* ws = (char*)d_ws;
    float*          Lp = (float*)ws;                          // 4 MB
    unsigned short* R2 = (unsigned short*)(ws + (4 << 20));   // 2 MB

    mfma_gemm_kernel<<<dim3(64, 8), 256, 0, stream>>>(x, W, b_lin, Lp, R2);
    attn_kernel<<<512, 512, 0, stream>>>(x, Lp, (const unsigned int*)R2, a, bias, out);
}